// Round 1
// 874.753 us; speedup vs baseline: 1.1410x; 1.1410x over previous
//
#include <hip/hip_runtime.h>
#include <math.h>

#define NTOK 1024
#define NHID 2048
#define NQKV 6144
#define NHEADS 16
#define DHEAD 128
#define ABLK 256
#define NEXPERT 8
#define NFFN 2048
#define EPS_LN 1e-5f
#define EPS_ATTN 1.1920929e-7f

typedef __bf16 bf8v __attribute__((ext_vector_type(8)));
typedef __bf16 bf4v __attribute__((ext_vector_type(4)));
typedef float f4v __attribute__((ext_vector_type(4)));

static __device__ __forceinline__ f4v mfma16(bf8v a, bf8v b, f4v c) {
  return __builtin_amdgcn_mfma_f32_16x16x32_bf16(a, b, c, 0, 0, 0);
}

static __device__ __forceinline__ void gl2lds16(const float* g, float* l) {
  __builtin_amdgcn_global_load_lds(
      (const __attribute__((address_space(1))) float*)g,
      (__attribute__((address_space(3))) float*)l, 16, 0, 0);
}

// ---------------- RMSNorm: one row (2048) per 256-thread block ----------------
__global__ __launch_bounds__(256) void rms_kernel(const float* __restrict__ in,
                                                  const float* __restrict__ w,
                                                  float* __restrict__ out,
                                                  const float* __restrict__ gate,
                                                  float* __restrict__ copy_out,
                                                  float eps) {
  const int row = blockIdx.x, tid = threadIdx.x;
  const float* p = in + (size_t)row * NHID;
  float4 v0 = *(const float4*)(p + 4 * tid);
  float4 v1 = *(const float4*)(p + 1024 + 4 * tid);
  float ss = v0.x * v0.x + v0.y * v0.y + v0.z * v0.z + v0.w * v0.w
           + v1.x * v1.x + v1.y * v1.y + v1.z * v1.z + v1.w * v1.w;
  for (int off = 32; off > 0; off >>= 1) ss += __shfl_down(ss, off);
  __shared__ float red[4];
  const int wv = tid >> 6, ln = tid & 63;
  if (ln == 0) red[wv] = ss;
  __syncthreads();
  const float tot = red[0] + red[1] + red[2] + red[3];
  const float rinv = rsqrtf(tot * (1.f / NHID) + eps);
  float4 w0 = *(const float4*)(w + 4 * tid);
  float4 w1 = *(const float4*)(w + 1024 + 4 * tid);
  float4 o0, o1;
  o0.x = v0.x * rinv * w0.x; o0.y = v0.y * rinv * w0.y;
  o0.z = v0.z * rinv * w0.z; o0.w = v0.w * rinv * w0.w;
  o1.x = v1.x * rinv * w1.x; o1.y = v1.y * rinv * w1.y;
  o1.z = v1.z * rinv * w1.z; o1.w = v1.w * rinv * w1.w;
  if (gate) {
    const float* gp = gate + (size_t)row * NHID;
    float4 g0 = *(const float4*)(gp + 4 * tid);
    float4 g1 = *(const float4*)(gp + 1024 + 4 * tid);
    o0.x *= g0.x; o0.y *= g0.y; o0.z *= g0.z; o0.w *= g0.w;
    o1.x *= g1.x; o1.y *= g1.y; o1.z *= g1.z; o1.w *= g1.w;
  }
  *(float4*)(out + (size_t)row * NHID + 4 * tid) = o0;
  *(float4*)(out + (size_t)row * NHID + 1024 + 4 * tid) = o1;
  if (copy_out) {
    *(float4*)(copy_out + (size_t)row * NHID + 4 * tid) = v0;
    *(float4*)(copy_out + (size_t)row * NHID + 1024 + 4 * tid) = v1;
  }
}

// ---------------- Generic C = act(A @ B^T) GEMM, bf16 MFMA ----------------
// Tile: 128 M x 64 N x 32 K. fp32 tiles staged via async global_load_lds with
// 16B XOR swizzle (chunk ^ (row&7)); fragments read with 2x ds_read_b128 and
// cvt to bf16. T3 "2-phase" pipeline: double-buffered LDS (48 KB), issue
// next-tile global_load_lds BEFORE computing current tile, single
// vmcnt(0)+s_barrier per K-step AFTER the MFMAs -> HBM latency hides under
// compute instead of serializing with it. 3 blocks/CU.
enum { GM_QKV = 0, GM_GATE = 1, GM_AOUT = 2, GM_MOE1 = 3, GM_MOE3 = 4, GM_MOE2 = 5 };

struct GArgs {
  const float* A; const float* B; float* C;
  const float* res;
  float* q_s; float* k_s; float* v_s;
  const int* perm; const int* segoff; const float* pw;
  float* outp;
  int N, K;
};

template <int MODE>
__global__ __launch_bounds__(256, 3) void gemm_bt(GArgs g) {
  const int n0 = blockIdx.x * 64;
  const int m0 = blockIdx.y * 128;
  int segbase = 0, cnt = 0x40000000, e = 0;
  if constexpr (MODE >= GM_MOE1) {
    e = blockIdx.z;
    segbase = g.segoff[e];
    cnt = g.segoff[e + 1] - segbase;
    if (m0 >= cnt) return;
  }
  const float* Bp = g.B + (size_t)e * g.N * g.K + (size_t)n0 * g.K;
  __shared__ float As[2][128 * 32];
  __shared__ float Bs[2][64 * 32];
  const int tid = threadIdx.x;
  const int w = tid >> 6, lane = tid & 63;
  const int wm = (w >> 1) * 64, wn = (w & 1) * 32;
  const int lm = lane & 15, quad = lane >> 4;
  const int lr = lane >> 3;                  // row within 8-row staging group
  const int coff = ((lane & 7) ^ lr) * 4;    // swizzled col offset (floats)
  const int K = g.K;

  const float* aptr[4];
  const float* bptr[2];
#pragma unroll
  for (int qi = 0; qi < 4; qi++) {
    const int r = (w * 4 + qi) * 8 + lr;     // 0..127
    const int m = m0 + r;
    long grow;
    if constexpr (MODE == GM_MOE1 || MODE == GM_MOE3) {
      int mm = m < cnt ? m : cnt - 1;
      grow = g.perm[segbase + mm];
    } else if constexpr (MODE == GM_MOE2) {
      grow = segbase + (m < cnt ? m : cnt - 1);
    } else {
      grow = m;
    }
    aptr[qi] = g.A + (size_t)grow * K + coff;
  }
#pragma unroll
  for (int qi = 0; qi < 2; qi++) {
    const int r = (w * 2 + qi) * 8 + lr;     // 0..63
    bptr[qi] = Bp + (size_t)r * K + coff;
  }

  const f4v fz = {0.f, 0.f, 0.f, 0.f};
  f4v acc[4][2];
#pragma unroll
  for (int i = 0; i < 4; i++) {
    acc[i][0] = fz; acc[i][1] = fz;
  }

  const int KT = K >> 5;
  // ---- prologue: stage tile 0 into buffer 0, drain, barrier ----
#pragma unroll
  for (int qi = 0; qi < 4; qi++) gl2lds16(aptr[qi], &As[0][(w * 4 + qi) * 256]);
#pragma unroll
  for (int qi = 0; qi < 2; qi++) gl2lds16(bptr[qi], &Bs[0][(w * 2 + qi) * 256]);
  asm volatile("s_waitcnt vmcnt(0)" ::: "memory");
  __builtin_amdgcn_s_barrier();

  for (int t = 0; t < KT; ++t) {
    const int cur = t & 1;
    // issue NEXT tile's loads first -> latency overlaps this tile's compute
    if (t + 1 < KT) {
      const int k1 = (t + 1) << 5;
#pragma unroll
      for (int qi = 0; qi < 4; qi++)
        gl2lds16(aptr[qi] + k1, &As[cur ^ 1][(w * 4 + qi) * 256]);
#pragma unroll
      for (int qi = 0; qi < 2; qi++)
        gl2lds16(bptr[qi] + k1, &Bs[cur ^ 1][(w * 2 + qi) * 256]);
    }
    // compute from buf[cur] (staged + drained + barriered last iteration)
    bf8v af[4], bfv[2];
    const int sw = lm & 7;
#pragma unroll
    for (int i = 0; i < 4; i++) {
      const int ra = wm + i * 16 + lm;
      const float4 x0 = *(const float4*)&As[cur][ra * 32 + (((quad * 2) ^ sw) << 2)];
      const float4 x1 = *(const float4*)&As[cur][ra * 32 + (((quad * 2 + 1) ^ sw) << 2)];
      bf8v t8;
      t8[0] = (__bf16)x0.x; t8[1] = (__bf16)x0.y; t8[2] = (__bf16)x0.z; t8[3] = (__bf16)x0.w;
      t8[4] = (__bf16)x1.x; t8[5] = (__bf16)x1.y; t8[6] = (__bf16)x1.z; t8[7] = (__bf16)x1.w;
      af[i] = t8;
    }
#pragma unroll
    for (int j = 0; j < 2; j++) {
      const int rb = wn + j * 16 + lm;
      const float4 x0 = *(const float4*)&Bs[cur][rb * 32 + (((quad * 2) ^ sw) << 2)];
      const float4 x1 = *(const float4*)&Bs[cur][rb * 32 + (((quad * 2 + 1) ^ sw) << 2)];
      bf8v t8;
      t8[0] = (__bf16)x0.x; t8[1] = (__bf16)x0.y; t8[2] = (__bf16)x0.z; t8[3] = (__bf16)x0.w;
      t8[4] = (__bf16)x1.x; t8[5] = (__bf16)x1.y; t8[6] = (__bf16)x1.z; t8[7] = (__bf16)x1.w;
      bfv[j] = t8;
    }
#pragma unroll
    for (int i = 0; i < 4; i++)
#pragma unroll
      for (int j = 0; j < 2; j++) acc[i][j] = mfma16(af[i], bfv[j], acc[i][j]);
    // one drain+barrier per K-step: next tile landed, this buffer free to reuse
    asm volatile("s_waitcnt vmcnt(0) lgkmcnt(0)" ::: "memory");
    __builtin_amdgcn_s_barrier();
  }

#pragma unroll
  for (int i = 0; i < 4; i++) {
#pragma unroll
    for (int r = 0; r < 4; r++) {
      const int m = m0 + wm + i * 16 + quad * 4 + r;
      int tok = 0;
      float wgt = 0.f;
      if constexpr (MODE == GM_MOE2) {
        if (m < cnt) { tok = g.perm[segbase + m]; wgt = g.pw[segbase + m]; }
      }
#pragma unroll
      for (int j = 0; j < 2; j++) {
        const int col = n0 + wn + j * 16 + lm;
        float v = acc[i][j][r];
        if constexpr (MODE == GM_QKV) {
          v = v / (1.f + expf(-v));
          int head = col / 384;
          int rem = col - head * 384;
          int which = rem >> 7;
          int d = rem & 127;
          float* dst = which == 0 ? g.q_s : (which == 1 ? g.k_s : g.v_s);
          dst[((size_t)head * NTOK + m) * DHEAD + d] = v;
        } else if constexpr (MODE == GM_GATE) {
          g.C[(size_t)m * g.N + col] = 1.f / (1.f + expf(-v));
        } else if constexpr (MODE == GM_AOUT) {
          g.C[(size_t)m * g.N + col] = v + g.res[(size_t)m * g.N + col];
        } else if constexpr (MODE == GM_MOE1) {
          if (m < cnt) g.C[(size_t)(segbase + m) * g.N + col] = v / (1.f + expf(-v));
        } else if constexpr (MODE == GM_MOE3) {
          if (m < cnt) {
            size_t ix = (size_t)(segbase + m) * g.N + col;
            g.C[ix] = v * g.res[ix];
          }
        } else if constexpr (MODE == GM_MOE2) {
          if (m < cnt) atomicAdd(&g.outp[(size_t)tok * NHID + col], wgt * v);
        }
      }
    }
  }
}

// ---------------- Lightning attention pass 1: S(h,b) = (k*kdecay)^T @ v ----------------
__global__ __launch_bounds__(512) void attn_pass1(const float* __restrict__ k_s,
                                                  const float* __restrict__ v_s,
                                                  const float* __restrict__ slope,
                                                  float* __restrict__ S) {
  const int h = blockIdx.x >> 2, b = blockIdx.x & 3;
  const float s = slope[h];
  __shared__ __bf16 kT[128][40] __attribute__((aligned(16)));
  __shared__ __bf16 vT[128][40] __attribute__((aligned(16)));
  const int tid = threadIdx.x, wave = tid >> 6, lane = tid & 63;
  const int lm = lane & 15, quad = lane >> 4;
  const float* kb = k_s + ((size_t)h * NTOK + b * ABLK) * DHEAD;
  const float* vb = v_s + ((size_t)h * NTOK + b * ABLK) * DHEAD;
  const int sd = tid & 127, sg = (tid >> 7) * 8;
  const f4v fz = {0.f, 0.f, 0.f, 0.f};
  f4v acc[8];
#pragma unroll
  for (int j = 0; j < 8; j++) acc[j] = fz;
  for (int ic = 0; ic < 8; ic++) {
    __syncthreads();
    bf8v kq, vq;
#pragma unroll
    for (int ii = 0; ii < 8; ii++) {
      int ig = ic * 32 + sg + ii;
      float kd = expf(-s * (float)(ABLK - 1 - ig));
      kq[ii] = (__bf16)(kb[(size_t)ig * DHEAD + sd] * kd);
      vq[ii] = (__bf16)(vb[(size_t)ig * DHEAD + sd]);
    }
    *(bf8v*)&kT[sd][sg] = kq;
    *(bf8v*)&vT[sd][sg] = vq;
    __syncthreads();
    bf8v a = *(const bf8v*)&kT[wave * 16 + lm][quad * 8];
#pragma unroll
    for (int j = 0; j < 8; j++) {
      bf8v bb = *(const bf8v*)&vT[j * 16 + lm][quad * 8];
      acc[j] = mfma16(a, bb, acc[j]);
    }
  }
  float* Sp = S + (size_t)(h * 4 + b) * (128 * 128);
#pragma unroll
  for (int j = 0; j < 8; j++)
#pragma unroll
    for (int r = 0; r < 4; r++)
      Sp[(size_t)(wave * 16 + quad * 4 + r) * 128 + j * 16 + lm] = acc[j][r];
}

// ---------------- Lightning attention pass 2: o = qdecay*(q@kv_in) + (qk*diag)@v ----------------
__global__ __launch_bounds__(512) void attn_pass2(const float* __restrict__ q_s,
                                                  const float* __restrict__ k_s,
                                                  const float* __restrict__ v_s,
                                                  const float* __restrict__ slope,
                                                  const float* __restrict__ S,
                                                  float* __restrict__ attn_raw) {
  const int h = blockIdx.x >> 2, b = blockIdx.x & 3;
  const float s = slope[h];
  __shared__ __bf16 kvb[128][136] __attribute__((aligned(16)));  // [e][d]
  __shared__ __bf16 vT[128][40] __attribute__((aligned(16)));    // [e][i-chunk]
  __shared__ __bf16 ki[32][136] __attribute__((aligned(16)));    // [i][d]
  __shared__ __bf16 qkb[256][40] __attribute__((aligned(16)));   // [m][i-chunk]
  const int tid = threadIdx.x, w = tid >> 6, lane = tid & 63;
  const int lm = lane & 15, quad = lane >> 4;
  // ---- build decayed KV prefix state in B-layout ----
  {
    const int sd = tid >> 2;
    const int e0 = (tid & 3) * 32;
    float vals[32];
#pragma unroll
    for (int u = 0; u < 32; u++) vals[u] = 0.f;
    for (int j = 0; j < b; j++) {
      float c = expf(-s * 256.f * (float)(b - 1 - j));
      const float* Sp = S + (size_t)(h * 4 + j) * (128 * 128) + (size_t)sd * 128 + e0;
#pragma unroll
      for (int u4 = 0; u4 < 8; u4++) {
        float4 sv = *(const float4*)(Sp + u4 * 4);
        vals[u4 * 4 + 0] += c * sv.x; vals[u4 * 4 + 1] += c * sv.y;
        vals[u4 * 4 + 2] += c * sv.z; vals[u4 * 4 + 3] += c * sv.w;
      }
    }
#pragma unroll
    for (int u = 0; u < 32; u++) kvb[e0 + u][sd] = (__bf16)vals[u];
  }
  __syncthreads();
  const float* qb = q_s + ((size_t)h * NTOK + b * ABLK) * DHEAD;
  const float* kb = k_s + ((size_t)h * NTOK + b * ABLK) * DHEAD;
  const float* vb = v_s + ((size_t)h * NTOK + b * ABLK) * DHEAD;
  // ---- q fragments (raw, no decay) ----
  bf8v aq[2][4];
#pragma unroll
  for (int mf = 0; mf < 2; mf++) {
    const int m = w * 32 + mf * 16 + lm;
#pragma unroll
    for (int kc = 0; kc < 4; kc++) {
      const float* pp = qb + (size_t)m * DHEAD + kc * 32 + quad * 8;
      float4 u0 = *(const float4*)pp;
      float4 u1 = *(const float4*)(pp + 4);
      bf8v t;
      t[0] = (__bf16)u0.x; t[1] = (__bf16)u0.y; t[2] = (__bf16)u0.z; t[3] = (__bf16)u0.w;
      t[4] = (__bf16)u1.x; t[5] = (__bf16)u1.y; t[6] = (__bf16)u1.z; t[7] = (__bf16)u1.w;
      aq[mf][kc] = t;
    }
  }
  const f4v fz = {0.f, 0.f, 0.f, 0.f};
  f4v accO[2][8];
#pragma unroll
  for (int mf = 0; mf < 2; mf++)
#pragma unroll
    for (int nf = 0; nf < 8; nf++) accO[mf][nf] = fz;
  // ---- o_nd = q @ kv_in ----
#pragma unroll
  for (int kc = 0; kc < 4; kc++) {
#pragma unroll
    for (int nf = 0; nf < 8; nf++) {
      bf8v bb = *(const bf8v*)&kvb[nf * 16 + lm][kc * 32 + quad * 8];
      accO[0][nf] = mfma16(aq[0][kc], bb, accO[0][nf]);
      accO[1][nf] = mfma16(aq[1][kc], bb, accO[1][nf]);
    }
  }
  // scale rows by q_decay
#pragma unroll
  for (int mf = 0; mf < 2; mf++) {
#pragma unroll
    for (int r = 0; r < 4; r++) {
      const int m = w * 32 + mf * 16 + quad * 4 + r;
      const float qd = expf(-s * (float)(m + 1));
#pragma unroll
      for (int nf = 0; nf < 8; nf++) accO[mf][nf][r] *= qd;
    }
  }
  // ---- intra-block: chunks of 32 keys ----
  for (int ic = 0; ic < 8; ic++) {
    __syncthreads();
    {
      const int si = tid >> 4, dc = (tid & 15) * 8;
      const float* pp = kb + (size_t)(ic * 32 + si) * DHEAD + dc;
      float4 u0 = *(const float4*)pp;
      float4 u1 = *(const float4*)(pp + 4);
      bf8v t;
      t[0] = (__bf16)u0.x; t[1] = (__bf16)u0.y; t[2] = (__bf16)u0.z; t[3] = (__bf16)u0.w;
      t[4] = (__bf16)u1.x; t[5] = (__bf16)u1.y; t[6] = (__bf16)u1.z; t[7] = (__bf16)u1.w;
      *(bf8v*)&ki[si][dc] = t;
    }
    {
      const int se = tid & 127, sg = (tid >> 7) * 8;
      bf8v t;
#pragma unroll
      for (int ii = 0; ii < 8; ii++)
        t[ii] = (__bf16)vb[(size_t)(ic * 32 + sg + ii) * DHEAD + se];
      *(bf8v*)&vT[se][sg] = t;
    }
    __syncthreads();
    f4v acc2[2][2];
    acc2[0][0] = fz; acc2[0][1] = fz; acc2[1][0] = fz; acc2[1][1] = fz;
#pragma unroll
    for (int kc = 0; kc < 4; kc++) {
#pragma unroll
      for (int f = 0; f < 2; f++) {
        bf8v bk = *(const bf8v*)&ki[f * 16 + lm][kc * 32 + quad * 8];
        acc2[0][f] = mfma16(aq[0][kc], bk, acc2[0][f]);
        acc2[1][f] = mfma16(aq[1][kc], bk, acc2[1][f]);
      }
    }
#pragma unroll
    for (int mf = 0; mf < 2; mf++) {
#pragma unroll
      for (int f = 0; f < 2; f++) {
#pragma unroll
        for (int r = 0; r < 4; r++) {
          const int m = w * 32 + mf * 16 + quad * 4 + r;
          const int i = ic * 32 + f * 16 + lm;
          float v = acc2[mf][f][r];
          v = (m >= i) ? v * expf(-s * (float)(m - i)) : 0.f;
          qkb[m][f * 16 + lm] = (__bf16)v;
        }
      }
    }
    __syncthreads();
#pragma unroll
    for (int mf = 0; mf < 2; mf++) {
      bf8v aqk = *(const bf8v*)&qkb[w * 32 + mf * 16 + lm][quad * 8];
#pragma unroll
      for (int nf = 0; nf < 8; nf++) {
        bf8v bv = *(const bf8v*)&vT[nf * 16 + lm][quad * 8];
        accO[mf][nf] = mfma16(aqk, bv, accO[mf][nf]);
      }
    }
  }
  float* op = attn_raw + (size_t)(b * ABLK) * NHID + h * DHEAD;
#pragma unroll
  for (int mf = 0; mf < 2; mf++)
#pragma unroll
    for (int r = 0; r < 4; r++) {
      const int m = w * 32 + mf * 16 + quad * 4 + r;
#pragma unroll
      for (int nf = 0; nf < 8; nf++)
        op[(size_t)m * NHID + nf * 16 + lm] = accO[mf][nf][r];
    }
}

// ---------------- Router: fp32 logits, top-2 ----------------
__global__ __launch_bounds__(256) void router_kernel(const float* __restrict__ h2,
                                                     const float* __restrict__ rw,
                                                     int* __restrict__ eidx,
                                                     float* __restrict__ ew) {
  const int wave = threadIdx.x >> 6, lane = threadIdx.x & 63;
  const int t = blockIdx.x * 4 + wave;
  float a[8];
#pragma unroll
  for (int e = 0; e < 8; e++) a[e] = 0.f;
  for (int d = lane; d < NHID; d += 64) {
    float xv = h2[(size_t)t * NHID + d];
#pragma unroll
    for (int e = 0; e < 8; e++) a[e] += xv * rw[(size_t)e * NHID + d];
  }
#pragma unroll
  for (int e = 0; e < 8; e++)
    for (int off = 32; off > 0; off >>= 1) a[e] += __shfl_down(a[e], off);
  if (lane == 0) {
    int i1 = 0;
#pragma unroll
    for (int e = 1; e < 8; e++)
      if (a[e] > a[i1]) i1 = e;
    int i2 = i1 == 0 ? 1 : 0;
#pragma unroll
    for (int e = 0; e < 8; e++) {
      if (e == i1 || e == i2) continue;
      if (a[e] > a[i2]) i2 = e;
    }
    float be = expf(a[i2] - a[i1]);
    float w1 = 1.f / (1.f + be), w2 = be / (1.f + be);
    eidx[2 * t] = i1; eidx[2 * t + 1] = i2;
    ew[2 * t] = w1; ew[2 * t + 1] = w2;
  }
}

__global__ __launch_bounds__(256) void build_lists(const int* __restrict__ eidx,
                                                   const float* __restrict__ ew,
                                                   int* __restrict__ segoff,
                                                   int* __restrict__ perm,
                                                   float* __restrict__ pw) {
  __shared__ int cnt[8], cur[8], offs[9];
  const int tid = threadIdx.x;
  if (tid < 8) cnt[tid] = 0;
  __syncthreads();
  for (int t = tid; t < NTOK; t += 256) {
    atomicAdd(&cnt[eidx[2 * t]], 1);
    atomicAdd(&cnt[eidx[2 * t + 1]], 1);
  }
  __syncthreads();
  if (tid == 0) {
    int o = 0;
    for (int e = 0; e < 8; e++) { offs[e] = o; o += cnt[e]; }
    offs[8] = o;
    for (int e = 0; e < 9; e++) segoff[e] = offs[e];
  }
  __syncthreads();
  if (tid < 8) cur[tid] = offs[tid];
  __syncthreads();
  for (int t = tid; t < NTOK; t += 256) {
    for (int k = 0; k < 2; k++) {
      int e = eidx[2 * t + k];
      int pos = atomicAdd(&cur[e], 1);
      perm[pos] = t;
      pw[pos] = ew[2 * t + k];
    }
  }
}

// ---------------- launch ----------------
extern "C" void kernel_launch(void* const* d_in, const int* in_sizes, int n_in,
                              void* d_out, int out_size, void* d_ws, size_t ws_size,
                              hipStream_t stream) {
  (void)in_sizes; (void)n_in; (void)out_size; (void)ws_size;
  const float* x        = (const float*)d_in[0];
  const float* slope    = (const float*)d_in[1];
  const float* ln1_w    = (const float*)d_in[2];
  const float* ln2_w    = (const float*)d_in[3];
  const float* qkv_w    = (const float*)d_in[4];
  const float* ogate_w  = (const float*)d_in[5];
  const float* anorm_w  = (const float*)d_in[6];
  const float* aout_w   = (const float*)d_in[7];
  const float* router_w = (const float*)d_in[8];
  const float* w1       = (const float*)d_in[9];
  const float* w2       = (const float*)d_in[10];
  const float* w3       = (const float*)d_in[11];
  float* out = (float*)d_out;
  float* ws  = (float*)d_ws;

  const size_t MW = (size_t)NTOK * NHID;  // 2M floats
  float* a_ln     = ws;                   // reused as "ag" after gate GEMM
  float* q_s      = ws + MW;
  float* k_s      = ws + 2 * MW;          // reused as h_res
  float* v_s      = ws + 3 * MW;          // reused as h2
  float* Sbuf     = ws + 4 * MW;          // 1M floats
  float* attn_raw = ws + 4 * MW + MW / 2;
  float* gatebuf  = ws + 5 * MW + MW / 2;
  float* t1       = ws + 4 * MW + MW / 2; // reuses attn_raw+gate after they die
  float* rbase    = ws + 6 * MW + MW / 2;
  int*   eidx   = (int*)rbase;
  float* ew     = rbase + 2048;
  int*   segoff = (int*)(rbase + 4096);
  int*   perm   = (int*)(rbase + 4112);
  float* pw     = rbase + 6160;
  float* h_res = k_s;
  float* h2    = v_s;
  float* ag    = a_ln;

  // 1. ln1
  rms_kernel<<<dim3(NTOK), dim3(256), 0, stream>>>(x, ln1_w, a_ln, nullptr, nullptr, EPS_LN);
  // 2. qkv = silu(a_ln @ qkv_w^T), split to q/k/v [h][t][d]
  {
    GArgs g{}; g.A = a_ln; g.B = qkv_w; g.q_s = q_s; g.k_s = k_s; g.v_s = v_s;
    g.N = NQKV; g.K = NHID;
    gemm_bt<GM_QKV><<<dim3(NQKV / 64, NTOK / 128), dim3(256), 0, stream>>>(g);
  }
  // 3/4. attention
  attn_pass1<<<dim3(64), dim3(512), 0, stream>>>(k_s, v_s, slope, Sbuf);
  attn_pass2<<<dim3(64), dim3(512), 0, stream>>>(q_s, k_s, v_s, slope, Sbuf, attn_raw);
  // 5. gate = sigmoid(a_ln @ ogate_w^T)
  {
    GArgs g{}; g.A = a_ln; g.B = ogate_w; g.C = gatebuf; g.N = NHID; g.K = NHID;
    gemm_bt<GM_GATE><<<dim3(32, 8), dim3(256), 0, stream>>>(g);
  }
  // 6. ag = rmsnorm(attn_raw)*anorm_w*gate   (overwrites a_ln)
  rms_kernel<<<dim3(NTOK), dim3(256), 0, stream>>>(attn_raw, anorm_w, ag, gatebuf, nullptr, EPS_ATTN);
  // 7. h_res = ag @ aout_w^T + x
  {
    GArgs g{}; g.A = ag; g.B = aout_w; g.C = h_res; g.res = x; g.N = NHID; g.K = NHID;
    gemm_bt<GM_AOUT><<<dim3(32, 8), dim3(256), 0, stream>>>(g);
  }
  // 8. h2 = rmsnorm(h_res, ln2); out = h_res (residual init)
  rms_kernel<<<dim3(NTOK), dim3(256), 0, stream>>>(h_res, ln2_w, h2, nullptr, out, EPS_LN);
  // 9. router (fp32)
  router_kernel<<<dim3(NTOK / 4), dim3(256), 0, stream>>>(h2, router_w, eidx, ew);
  // 10. bucket tokens by expert
  build_lists<<<dim3(1), dim3(256), 0, stream>>>(eidx, ew, segoff, perm, pw);
  // 11. t1 = silu(h2[gather] @ w1^T)
  {
    GArgs g{}; g.A = h2; g.B = w1; g.C = t1; g.perm = perm; g.segoff = segoff;
    g.N = NFFN; g.K = NHID;
    gemm_bt<GM_MOE1><<<dim3(32, 16, 8), dim3(256), 0, stream>>>(g);
  }
  // 12. t1 = t1 * (h2[gather] @ w3^T)
  {
    GArgs g{}; g.A = h2; g.B = w3; g.C = t1; g.res = t1; g.perm = perm; g.segoff = segoff;
    g.N = NFFN; g.K = NHID;
    gemm_bt<GM_MOE3><<<dim3(32, 16, 8), dim3(256), 0, stream>>>(g);
  }
  // 13. out[token] += weight * (t1 @ w2^T)
  {
    GArgs g{}; g.A = t1; g.B = w2; g.outp = out; g.perm = perm; g.segoff = segoff; g.pw = pw;
    g.N = NHID; g.K = NFFN;
    gemm_bt<GM_MOE2><<<dim3(32, 16, 8), dim3(256), 0, stream>>>(g);
  }
}

// Round 2
// 824.683 us; speedup vs baseline: 1.2103x; 1.0607x over previous
//
#include <hip/hip_runtime.h>
#include <math.h>

#define NTOK 1024
#define NHID 2048
#define NQKV 6144
#define NHEADS 16
#define DHEAD 128
#define ABLK 256
#define NEXPERT 8
#define NFFN 2048
#define EPS_LN 1e-5f
#define EPS_ATTN 1.1920929e-7f

typedef __bf16 bf8v __attribute__((ext_vector_type(8)));
typedef __bf16 bf4v __attribute__((ext_vector_type(4)));
typedef float f4v __attribute__((ext_vector_type(4)));

static __device__ __forceinline__ f4v mfma16(bf8v a, bf8v b, f4v c) {
  return __builtin_amdgcn_mfma_f32_16x16x32_bf16(a, b, c, 0, 0, 0);
}

static __device__ __forceinline__ void gl2lds16(const void* g, void* l) {
  __builtin_amdgcn_global_load_lds(
      (const __attribute__((address_space(1))) unsigned int*)g,
      (__attribute__((address_space(3))) unsigned int*)l, 16, 0, 0);
}

// ---------------- RMSNorm: one row (2048) per 256-thread block ----------------
// Writes bf16 (GEMM-A operand) always; optional fp32 copy (router) and raw
// input copy (residual init).
__global__ __launch_bounds__(256) void rms_kernel(const float* __restrict__ in,
                                                  const float* __restrict__ w,
                                                  __bf16* __restrict__ out_bf,
                                                  const float* __restrict__ gate,
                                                  float* __restrict__ copy_out,
                                                  float* __restrict__ out_f32,
                                                  float eps) {
  const int row = blockIdx.x, tid = threadIdx.x;
  const float* p = in + (size_t)row * NHID;
  float4 v0 = *(const float4*)(p + 4 * tid);
  float4 v1 = *(const float4*)(p + 1024 + 4 * tid);
  float ss = v0.x * v0.x + v0.y * v0.y + v0.z * v0.z + v0.w * v0.w
           + v1.x * v1.x + v1.y * v1.y + v1.z * v1.z + v1.w * v1.w;
  for (int off = 32; off > 0; off >>= 1) ss += __shfl_down(ss, off);
  __shared__ float red[4];
  const int wv = tid >> 6, ln = tid & 63;
  if (ln == 0) red[wv] = ss;
  __syncthreads();
  const float tot = red[0] + red[1] + red[2] + red[3];
  const float rinv = rsqrtf(tot * (1.f / NHID) + eps);
  float4 w0 = *(const float4*)(w + 4 * tid);
  float4 w1 = *(const float4*)(w + 1024 + 4 * tid);
  float4 o0, o1;
  o0.x = v0.x * rinv * w0.x; o0.y = v0.y * rinv * w0.y;
  o0.z = v0.z * rinv * w0.z; o0.w = v0.w * rinv * w0.w;
  o1.x = v1.x * rinv * w1.x; o1.y = v1.y * rinv * w1.y;
  o1.z = v1.z * rinv * w1.z; o1.w = v1.w * rinv * w1.w;
  if (gate) {
    const float* gp = gate + (size_t)row * NHID;
    float4 g0 = *(const float4*)(gp + 4 * tid);
    float4 g1 = *(const float4*)(gp + 1024 + 4 * tid);
    o0.x *= g0.x; o0.y *= g0.y; o0.z *= g0.z; o0.w *= g0.w;
    o1.x *= g1.x; o1.y *= g1.y; o1.z *= g1.z; o1.w *= g1.w;
  }
  bf4v b0, b1;
  b0[0] = (__bf16)o0.x; b0[1] = (__bf16)o0.y; b0[2] = (__bf16)o0.z; b0[3] = (__bf16)o0.w;
  b1[0] = (__bf16)o1.x; b1[1] = (__bf16)o1.y; b1[2] = (__bf16)o1.z; b1[3] = (__bf16)o1.w;
  *(bf4v*)(out_bf + (size_t)row * NHID + 4 * tid) = b0;
  *(bf4v*)(out_bf + (size_t)row * NHID + 1024 + 4 * tid) = b1;
  if (out_f32) {
    *(float4*)(out_f32 + (size_t)row * NHID + 4 * tid) = o0;
    *(float4*)(out_f32 + (size_t)row * NHID + 1024 + 4 * tid) = o1;
  }
  if (copy_out) {
    *(float4*)(copy_out + (size_t)row * NHID + 4 * tid) = v0;
    *(float4*)(copy_out + (size_t)row * NHID + 1024 + 4 * tid) = v1;
  }
}

// ---------------- Generic C = act(A @ B^T) GEMM ----------------
// A: bf16 (producer-converted), staged 128x32x2B via global_load_lds with
//    16B XOR swizzle (chunk ^ (row&3), 4 chunks/row) -> 1 ds_read_b128/frag, 0 cvt.
// B: fp32 weights, staged 64x32x4B, chunk ^ (row&7) swizzle, cvt at read.
// 3-deep LDS pipeline (48KB), counted s_waitcnt vmcnt(4) (4 gl2lds/wave/tile),
// single barrier per K-step. 3 blocks/CU.
enum { GM_QKV = 0, GM_GATE = 1, GM_AOUT = 2, GM_MOE1 = 3, GM_MOE3 = 4, GM_MOE2 = 5 };

struct GArgs {
  const __bf16* A; const float* B; void* C;
  const float* res;
  __bf16* q_s; __bf16* k_s; __bf16* v_s;
  const int* perm; const int* segoff; const float* pw;
  float* outp;
  int N, K;
};

template <int MODE>
__global__ __launch_bounds__(256, 3) void gemm_bt(GArgs g) {
  const int n0 = blockIdx.x * 64;
  const int m0 = blockIdx.y * 128;
  int segbase = 0, cnt = 0x40000000, e = 0;
  if constexpr (MODE >= GM_MOE1) {
    e = blockIdx.z;
    segbase = g.segoff[e];
    cnt = g.segoff[e + 1] - segbase;
    if (m0 >= cnt) return;
  }
  const float* Bp = g.B + (size_t)e * g.N * g.K + (size_t)n0 * g.K;
  __shared__ __bf16 As[3][128 * 32] __attribute__((aligned(16)));
  __shared__ float Bs[3][64 * 32] __attribute__((aligned(16)));
  const int tid = threadIdx.x;
  const int w = tid >> 6, lane = tid & 63;
  const int wm = (w >> 1) * 64, wn = (w & 1) * 32;
  const int lm = lane & 15, quad = lane >> 4;
  const int K = g.K;

  // A staging: 2 gl2lds/wave; lane -> row w*32+qi*16+(lane>>2), chunk lane&3.
  // global chunk = (lane&3) ^ (row&3) so that LDS read chunk quad^(row&3) is linear-free.
  const __bf16* aptr[2];
#pragma unroll
  for (int qi = 0; qi < 2; qi++) {
    const int r = w * 32 + qi * 16 + (lane >> 2);
    const int m = m0 + r;
    long grow;
    if constexpr (MODE == GM_MOE1 || MODE == GM_MOE3) {
      int mm = m < cnt ? m : cnt - 1;
      grow = g.perm[segbase + mm];
    } else if constexpr (MODE == GM_MOE2) {
      grow = segbase + (m < cnt ? m : cnt - 1);
    } else {
      grow = m;
    }
    const int gc = (lane & 3) ^ (r & 3);
    aptr[qi] = g.A + (size_t)grow * K + gc * 8;
  }
  // B staging: 2 gl2lds/wave; lane -> row (w*2+qi)*8+(lane>>3), chunk lane&7 (^row&7).
  const float* bptr[2];
  {
    const int lr = lane >> 3;
    const int coff = ((lane & 7) ^ lr) * 4;
#pragma unroll
    for (int qi = 0; qi < 2; qi++) {
      const int r = (w * 2 + qi) * 8 + lr;
      bptr[qi] = Bp + (size_t)r * K + coff;
    }
  }

  const f4v fz = {0.f, 0.f, 0.f, 0.f};
  f4v acc[4][2];
#pragma unroll
  for (int i = 0; i < 4; i++) {
    acc[i][0] = fz; acc[i][1] = fz;
  }

  const int KT = K >> 5;

#define STAGE(tt, bb)                                      \
  do {                                                     \
    const int kk_ = (tt) << 5;                             \
    gl2lds16(aptr[0] + kk_, &As[bb][(w * 32) * 32]);       \
    gl2lds16(aptr[1] + kk_, &As[bb][(w * 32 + 16) * 32]);  \
    gl2lds16(bptr[0] + kk_, &Bs[bb][(w * 16) * 32]);       \
    gl2lds16(bptr[1] + kk_, &Bs[bb][(w * 16 + 8) * 32]);   \
  } while (0)

  // prologue: tiles 0 and 1 in flight
  STAGE(0, 0);
  STAGE(1, 1);

  const int swa = lm & 3;   // A read swizzle (row&3)
  const int swb = lm & 7;   // B read swizzle (row&7)
  for (int t = 0; t < KT; ++t) {
    const int cur = t % 3;
    if (t + 1 < KT) {
      asm volatile("s_waitcnt vmcnt(4)" ::: "memory");  // tile t landed; t+1 in flight
    } else {
      asm volatile("s_waitcnt vmcnt(0)" ::: "memory");
    }
    __builtin_amdgcn_s_barrier();  // all waves: tile t ready; buf (t+2)%3 free
    if (t + 2 < KT) {
      const int nb = (t + 2) % 3;
      STAGE(t + 2, nb);
    }
    // ---- compute tile t ----
    bf8v af[4], bfv[2];
#pragma unroll
    for (int i = 0; i < 4; i++) {
      const int ra = wm + i * 16 + lm;
      af[i] = *(const bf8v*)&As[cur][ra * 32 + ((quad ^ swa) << 3)];
    }
#pragma unroll
    for (int j = 0; j < 2; j++) {
      const int rb = wn + j * 16 + lm;
      const float4 x0 = *(const float4*)&Bs[cur][rb * 32 + (((quad * 2) ^ swb) << 2)];
      const float4 x1 = *(const float4*)&Bs[cur][rb * 32 + (((quad * 2 + 1) ^ swb) << 2)];
      bf8v t8;
      t8[0] = (__bf16)x0.x; t8[1] = (__bf16)x0.y; t8[2] = (__bf16)x0.z; t8[3] = (__bf16)x0.w;
      t8[4] = (__bf16)x1.x; t8[5] = (__bf16)x1.y; t8[6] = (__bf16)x1.z; t8[7] = (__bf16)x1.w;
      bfv[j] = t8;
    }
#pragma unroll
    for (int i = 0; i < 4; i++)
#pragma unroll
      for (int j = 0; j < 2; j++) acc[i][j] = mfma16(af[i], bfv[j], acc[i][j]);
  }
#undef STAGE

#pragma unroll
  for (int i = 0; i < 4; i++) {
#pragma unroll
    for (int r = 0; r < 4; r++) {
      const int m = m0 + wm + i * 16 + quad * 4 + r;
      int tok = 0;
      float wgt = 0.f;
      if constexpr (MODE == GM_MOE2) {
        if (m < cnt) { tok = g.perm[segbase + m]; wgt = g.pw[segbase + m]; }
      }
#pragma unroll
      for (int j = 0; j < 2; j++) {
        const int col = n0 + wn + j * 16 + lm;
        float v = acc[i][j][r];
        if constexpr (MODE == GM_QKV) {
          v = v / (1.f + expf(-v));
          int head = col / 384;
          int rem = col - head * 384;
          int which = rem >> 7;
          int d = rem & 127;
          __bf16* dst = which == 0 ? g.q_s : (which == 1 ? g.k_s : g.v_s);
          dst[((size_t)head * NTOK + m) * DHEAD + d] = (__bf16)v;
        } else if constexpr (MODE == GM_GATE) {
          ((float*)g.C)[(size_t)m * g.N + col] = 1.f / (1.f + expf(-v));
        } else if constexpr (MODE == GM_AOUT) {
          ((float*)g.C)[(size_t)m * g.N + col] = v + g.res[(size_t)m * g.N + col];
        } else if constexpr (MODE == GM_MOE1) {
          if (m < cnt)
            ((__bf16*)g.C)[(size_t)(segbase + m) * g.N + col] = (__bf16)(v / (1.f + expf(-v)));
        } else if constexpr (MODE == GM_MOE3) {
          if (m < cnt) {
            size_t ix = (size_t)(segbase + m) * g.N + col;
            __bf16* tc = (__bf16*)g.C;
            tc[ix] = (__bf16)(v * (float)tc[ix]);
          }
        } else if constexpr (MODE == GM_MOE2) {
          if (m < cnt) atomicAdd(&g.outp[(size_t)tok * NHID + col], wgt * v);
        }
      }
    }
  }
}

// ---------------- Lightning attention pass 1: S(h,b) = (k*kdecay)^T @ v ----------------
__global__ __launch_bounds__(512) void attn_pass1(const __bf16* __restrict__ k_s,
                                                  const __bf16* __restrict__ v_s,
                                                  const float* __restrict__ slope,
                                                  float* __restrict__ S) {
  const int h = blockIdx.x >> 2, b = blockIdx.x & 3;
  const float s = slope[h];
  __shared__ __bf16 kT[128][40] __attribute__((aligned(16)));
  __shared__ __bf16 vT[128][40] __attribute__((aligned(16)));
  const int tid = threadIdx.x, wave = tid >> 6, lane = tid & 63;
  const int lm = lane & 15, quad = lane >> 4;
  const __bf16* kb = k_s + ((size_t)h * NTOK + b * ABLK) * DHEAD;
  const __bf16* vb = v_s + ((size_t)h * NTOK + b * ABLK) * DHEAD;
  const int sd = tid & 127, sg = (tid >> 7) * 8;
  const f4v fz = {0.f, 0.f, 0.f, 0.f};
  f4v acc[8];
#pragma unroll
  for (int j = 0; j < 8; j++) acc[j] = fz;
  for (int ic = 0; ic < 8; ic++) {
    __syncthreads();
    bf8v kq, vq;
#pragma unroll
    for (int ii = 0; ii < 8; ii++) {
      int ig = ic * 32 + sg + ii;
      float kd = expf(-s * (float)(ABLK - 1 - ig));
      kq[ii] = (__bf16)((float)kb[(size_t)ig * DHEAD + sd] * kd);
      vq[ii] = vb[(size_t)ig * DHEAD + sd];
    }
    *(bf8v*)&kT[sd][sg] = kq;
    *(bf8v*)&vT[sd][sg] = vq;
    __syncthreads();
    bf8v a = *(const bf8v*)&kT[wave * 16 + lm][quad * 8];
#pragma unroll
    for (int j = 0; j < 8; j++) {
      bf8v bb = *(const bf8v*)&vT[j * 16 + lm][quad * 8];
      acc[j] = mfma16(a, bb, acc[j]);
    }
  }
  float* Sp = S + (size_t)(h * 4 + b) * (128 * 128);
#pragma unroll
  for (int j = 0; j < 8; j++)
#pragma unroll
    for (int r = 0; r < 4; r++)
      Sp[(size_t)(wave * 16 + quad * 4 + r) * 128 + j * 16 + lm] = acc[j][r];
}

// ---------------- Lightning attention pass 2: o = qdecay*(q@kv_in) + (qk*diag)@v ----------------
__global__ __launch_bounds__(512) void attn_pass2(const __bf16* __restrict__ q_s,
                                                  const __bf16* __restrict__ k_s,
                                                  const __bf16* __restrict__ v_s,
                                                  const float* __restrict__ slope,
                                                  const float* __restrict__ S,
                                                  float* __restrict__ attn_raw) {
  const int h = blockIdx.x >> 2, b = blockIdx.x & 3;
  const float s = slope[h];
  __shared__ __bf16 kvb[128][136] __attribute__((aligned(16)));  // [e][d]
  __shared__ __bf16 vT[128][40] __attribute__((aligned(16)));    // [e][i-chunk]
  __shared__ __bf16 ki[32][136] __attribute__((aligned(16)));    // [i][d]
  __shared__ __bf16 qkb[256][40] __attribute__((aligned(16)));   // [m][i-chunk]
  const int tid = threadIdx.x, w = tid >> 6, lane = tid & 63;
  const int lm = lane & 15, quad = lane >> 4;
  // ---- build decayed KV prefix state in B-layout ----
  {
    const int sd = tid >> 2;
    const int e0 = (tid & 3) * 32;
    float vals[32];
#pragma unroll
    for (int u = 0; u < 32; u++) vals[u] = 0.f;
    for (int j = 0; j < b; j++) {
      float c = expf(-s * 256.f * (float)(b - 1 - j));
      const float* Sp = S + (size_t)(h * 4 + j) * (128 * 128) + (size_t)sd * 128 + e0;
#pragma unroll
      for (int u4 = 0; u4 < 8; u4++) {
        float4 sv = *(const float4*)(Sp + u4 * 4);
        vals[u4 * 4 + 0] += c * sv.x; vals[u4 * 4 + 1] += c * sv.y;
        vals[u4 * 4 + 2] += c * sv.z; vals[u4 * 4 + 3] += c * sv.w;
      }
    }
#pragma unroll
    for (int u = 0; u < 32; u++) kvb[e0 + u][sd] = (__bf16)vals[u];
  }
  __syncthreads();
  const __bf16* qb = q_s + ((size_t)h * NTOK + b * ABLK) * DHEAD;
  const __bf16* kb = k_s + ((size_t)h * NTOK + b * ABLK) * DHEAD;
  const __bf16* vb = v_s + ((size_t)h * NTOK + b * ABLK) * DHEAD;
  // ---- q fragments (raw, no decay) ----
  bf8v aq[2][4];
#pragma unroll
  for (int mf = 0; mf < 2; mf++) {
    const int m = w * 32 + mf * 16 + lm;
#pragma unroll
    for (int kc = 0; kc < 4; kc++)
      aq[mf][kc] = *(const bf8v*)(qb + (size_t)m * DHEAD + kc * 32 + quad * 8);
  }
  const f4v fz = {0.f, 0.f, 0.f, 0.f};
  f4v accO[2][8];
#pragma unroll
  for (int mf = 0; mf < 2; mf++)
#pragma unroll
    for (int nf = 0; nf < 8; nf++) accO[mf][nf] = fz;
  // ---- o_nd = q @ kv_in ----
#pragma unroll
  for (int kc = 0; kc < 4; kc++) {
#pragma unroll
    for (int nf = 0; nf < 8; nf++) {
      bf8v bb = *(const bf8v*)&kvb[nf * 16 + lm][kc * 32 + quad * 8];
      accO[0][nf] = mfma16(aq[0][kc], bb, accO[0][nf]);
      accO[1][nf] = mfma16(aq[1][kc], bb, accO[1][nf]);
    }
  }
  // scale rows by q_decay
#pragma unroll
  for (int mf = 0; mf < 2; mf++) {
#pragma unroll
    for (int r = 0; r < 4; r++) {
      const int m = w * 32 + mf * 16 + quad * 4 + r;
      const float qd = expf(-s * (float)(m + 1));
#pragma unroll
      for (int nf = 0; nf < 8; nf++) accO[mf][nf][r] *= qd;
    }
  }
  // ---- intra-block: chunks of 32 keys ----
  for (int ic = 0; ic < 8; ic++) {
    __syncthreads();
    {
      const int si = tid >> 4, dc = (tid & 15) * 8;
      *(bf8v*)&ki[si][dc] = *(const bf8v*)(kb + (size_t)(ic * 32 + si) * DHEAD + dc);
    }
    {
      const int se = tid & 127, sg = (tid >> 7) * 8;
      bf8v t;
#pragma unroll
      for (int ii = 0; ii < 8; ii++)
        t[ii] = vb[(size_t)(ic * 32 + sg + ii) * DHEAD + se];
      *(bf8v*)&vT[se][sg] = t;
    }
    __syncthreads();
    f4v acc2[2][2];
    acc2[0][0] = fz; acc2[0][1] = fz; acc2[1][0] = fz; acc2[1][1] = fz;
#pragma unroll
    for (int kc = 0; kc < 4; kc++) {
#pragma unroll
      for (int f = 0; f < 2; f++) {
        bf8v bk = *(const bf8v*)&ki[f * 16 + lm][kc * 32 + quad * 8];
        acc2[0][f] = mfma16(aq[0][kc], bk, acc2[0][f]);
        acc2[1][f] = mfma16(aq[1][kc], bk, acc2[1][f]);
      }
    }
#pragma unroll
    for (int mf = 0; mf < 2; mf++) {
#pragma unroll
      for (int f = 0; f < 2; f++) {
#pragma unroll
        for (int r = 0; r < 4; r++) {
          const int m = w * 32 + mf * 16 + quad * 4 + r;
          const int i = ic * 32 + f * 16 + lm;
          float v = acc2[mf][f][r];
          v = (m >= i) ? v * expf(-s * (float)(m - i)) : 0.f;
          qkb[m][f * 16 + lm] = (__bf16)v;
        }
      }
    }
    __syncthreads();
#pragma unroll
    for (int mf = 0; mf < 2; mf++) {
      bf8v aqk = *(const bf8v*)&qkb[w * 32 + mf * 16 + lm][quad * 8];
#pragma unroll
      for (int nf = 0; nf < 8; nf++) {
        bf8v bv = *(const bf8v*)&vT[nf * 16 + lm][quad * 8];
        accO[mf][nf] = mfma16(aqk, bv, accO[mf][nf]);
      }
    }
  }
  float* op = attn_raw + (size_t)(b * ABLK) * NHID + h * DHEAD;
#pragma unroll
  for (int mf = 0; mf < 2; mf++)
#pragma unroll
    for (int r = 0; r < 4; r++) {
      const int m = w * 32 + mf * 16 + quad * 4 + r;
#pragma unroll
      for (int nf = 0; nf < 8; nf++)
        op[(size_t)m * NHID + nf * 16 + lm] = accO[mf][nf][r];
    }
}

// ---------------- Router: fp32 logits, top-2 ----------------
__global__ __launch_bounds__(256) void router_kernel(const float* __restrict__ h2,
                                                     const float* __restrict__ rw,
                                                     int* __restrict__ eidx,
                                                     float* __restrict__ ew) {
  const int wave = threadIdx.x >> 6, lane = threadIdx.x & 63;
  const int t = blockIdx.x * 4 + wave;
  float a[8];
#pragma unroll
  for (int e = 0; e < 8; e++) a[e] = 0.f;
  for (int d = lane; d < NHID; d += 64) {
    float xv = h2[(size_t)t * NHID + d];
#pragma unroll
    for (int e = 0; e < 8; e++) a[e] += xv * rw[(size_t)e * NHID + d];
  }
#pragma unroll
  for (int e = 0; e < 8; e++)
    for (int off = 32; off > 0; off >>= 1) a[e] += __shfl_down(a[e], off);
  if (lane == 0) {
    int i1 = 0;
#pragma unroll
    for (int e = 1; e < 8; e++)
      if (a[e] > a[i1]) i1 = e;
    int i2 = i1 == 0 ? 1 : 0;
#pragma unroll
    for (int e = 0; e < 8; e++) {
      if (e == i1 || e == i2) continue;
      if (a[e] > a[i2]) i2 = e;
    }
    float be = expf(a[i2] - a[i1]);
    float w1 = 1.f / (1.f + be), w2 = be / (1.f + be);
    eidx[2 * t] = i1; eidx[2 * t + 1] = i2;
    ew[2 * t] = w1; ew[2 * t + 1] = w2;
  }
}

__global__ __launch_bounds__(256) void build_lists(const int* __restrict__ eidx,
                                                   const float* __restrict__ ew,
                                                   int* __restrict__ segoff,
                                                   int* __restrict__ perm,
                                                   float* __restrict__ pw) {
  __shared__ int cnt[8], cur[8], offs[9];
  const int tid = threadIdx.x;
  if (tid < 8) cnt[tid] = 0;
  __syncthreads();
  for (int t = tid; t < NTOK; t += 256) {
    atomicAdd(&cnt[eidx[2 * t]], 1);
    atomicAdd(&cnt[eidx[2 * t + 1]], 1);
  }
  __syncthreads();
  if (tid == 0) {
    int o = 0;
    for (int e = 0; e < 8; e++) { offs[e] = o; o += cnt[e]; }
    offs[8] = o;
    for (int e = 0; e < 9; e++) segoff[e] = offs[e];
  }
  __syncthreads();
  if (tid < 8) cur[tid] = offs[tid];
  __syncthreads();
  for (int t = tid; t < NTOK; t += 256) {
    for (int k = 0; k < 2; k++) {
      int e = eidx[2 * t + k];
      int pos = atomicAdd(&cur[e], 1);
      perm[pos] = t;
      pw[pos] = ew[2 * t + k];
    }
  }
}

// ---------------- launch ----------------
extern "C" void kernel_launch(void* const* d_in, const int* in_sizes, int n_in,
                              void* d_out, int out_size, void* d_ws, size_t ws_size,
                              hipStream_t stream) {
  (void)in_sizes; (void)n_in; (void)out_size; (void)ws_size;
  const float* x        = (const float*)d_in[0];
  const float* slope    = (const float*)d_in[1];
  const float* ln1_w    = (const float*)d_in[2];
  const float* ln2_w    = (const float*)d_in[3];
  const float* qkv_w    = (const float*)d_in[4];
  const float* ogate_w  = (const float*)d_in[5];
  const float* anorm_w  = (const float*)d_in[6];
  const float* aout_w   = (const float*)d_in[7];
  const float* router_w = (const float*)d_in[8];
  const float* w1       = (const float*)d_in[9];
  const float* w2       = (const float*)d_in[10];
  const float* w3       = (const float*)d_in[11];
  float* out = (float*)d_out;
  float* ws  = (float*)d_ws;

  const size_t MW = (size_t)NTOK * NHID;  // 2M floats
  // slot 0: a_ln (bf16) -> later ag (bf16)
  // slot 1: q_s (bf16)
  // slot 2: k_s (bf16) -> later h_res (fp32)
  // slot 3: v_s (bf16) -> later h2 (bf16)
  // 4.0-4.5 MW: Sbuf (fp32)
  // 4.5-5.5 MW: attn_raw (fp32) -> later t1 (bf16, 4M elems = 8MB)
  // 5.5-6.5 MW: gatebuf (fp32) -> later h2f (fp32, router)
  __bf16* a_ln   = (__bf16*)ws;
  __bf16* q_s    = (__bf16*)(ws + MW);
  __bf16* k_s    = (__bf16*)(ws + 2 * MW);
  __bf16* v_s    = (__bf16*)(ws + 3 * MW);
  float* Sbuf    = ws + 4 * MW;
  float* attn_raw = ws + 4 * MW + MW / 2;
  float* gatebuf  = ws + 5 * MW + MW / 2;
  __bf16* t1     = (__bf16*)attn_raw;
  float* h2f     = gatebuf;
  float* rbase   = ws + 6 * MW + MW / 2;
  int*   eidx   = (int*)rbase;
  float* ew     = rbase + 2048;
  int*   segoff = (int*)(rbase + 4096);
  int*   perm   = (int*)(rbase + 4112);
  float* pw     = rbase + 6160;
  float* h_res  = ws + 2 * MW;
  __bf16* h2    = v_s;
  __bf16* ag    = a_ln;

  // 1. ln1 -> bf16
  rms_kernel<<<dim3(NTOK), dim3(256), 0, stream>>>(x, ln1_w, a_ln, nullptr, nullptr, nullptr, EPS_LN);
  // 2. qkv = silu(a_ln @ qkv_w^T), split to bf16 q/k/v [h][t][d]
  {
    GArgs g{}; g.A = a_ln; g.B = qkv_w; g.q_s = q_s; g.k_s = k_s; g.v_s = v_s;
    g.N = NQKV; g.K = NHID;
    gemm_bt<GM_QKV><<<dim3(NQKV / 64, NTOK / 128), dim3(256), 0, stream>>>(g);
  }
  // 3/4. attention (bf16 q/k/v)
  attn_pass1<<<dim3(64), dim3(512), 0, stream>>>(k_s, v_s, slope, Sbuf);
  attn_pass2<<<dim3(64), dim3(512), 0, stream>>>(q_s, k_s, v_s, slope, Sbuf, attn_raw);
  // 5. gate = sigmoid(a_ln @ ogate_w^T)  (fp32 out)
  {
    GArgs g{}; g.A = a_ln; g.B = ogate_w; g.C = gatebuf; g.N = NHID; g.K = NHID;
    gemm_bt<GM_GATE><<<dim3(32, 8), dim3(256), 0, stream>>>(g);
  }
  // 6. ag = rmsnorm(attn_raw)*anorm_w*gate -> bf16 (overwrites a_ln)
  rms_kernel<<<dim3(NTOK), dim3(256), 0, stream>>>(attn_raw, anorm_w, ag, gatebuf, nullptr, nullptr, EPS_ATTN);
  // 7. h_res = ag @ aout_w^T + x  (fp32)
  {
    GArgs g{}; g.A = ag; g.B = aout_w; g.C = h_res; g.res = x; g.N = NHID; g.K = NHID;
    gemm_bt<GM_AOUT><<<dim3(32, 8), dim3(256), 0, stream>>>(g);
  }
  // 8. h2 = rmsnorm(h_res, ln2) -> bf16 + fp32 (router); out = h_res copy
  rms_kernel<<<dim3(NTOK), dim3(256), 0, stream>>>(h_res, ln2_w, h2, nullptr, out, h2f, EPS_LN);
  // 9. router (fp32 h2)
  router_kernel<<<dim3(NTOK / 4), dim3(256), 0, stream>>>(h2f, router_w, eidx, ew);
  // 10. bucket tokens by expert
  build_lists<<<dim3(1), dim3(256), 0, stream>>>(eidx, ew, segoff, perm, pw);
  // 11. t1 = silu(h2[gather] @ w1^T) -> bf16
  {
    GArgs g{}; g.A = h2; g.B = w1; g.C = t1; g.perm = perm; g.segoff = segoff;
    g.N = NFFN; g.K = NHID;
    gemm_bt<GM_MOE1><<<dim3(32, 16, 8), dim3(256), 0, stream>>>(g);
  }
  // 12. t1 = t1 * (h2[gather] @ w3^T) -> bf16
  {
    GArgs g{}; g.A = h2; g.B = w3; g.C = t1; g.perm = perm; g.segoff = segoff;
    g.N = NFFN; g.K = NHID;
    gemm_bt<GM_MOE3><<<dim3(32, 16, 8), dim3(256), 0, stream>>>(g);
  }
  // 13. out[token] += weight * (t1 @ w2^T)
  {
    GArgs g{}; g.A = t1; g.B = w2; g.outp = out; g.perm = perm; g.segoff = segoff; g.pw = pw;
    g.N = NHID; g.K = NFFN;
    gemm_bt<GM_MOE2><<<dim3(32, 16, 8), dim3(256), 0, stream>>>(g);
  }
}

// Round 3
// 817.526 us; speedup vs baseline: 1.2209x; 1.0088x over previous
//
#include <hip/hip_runtime.h>
#include <math.h>

#define NTOK 1024
#define NHID 2048
#define NQKV 6144
#define NHEADS 16
#define DHEAD 128
#define ABLK 256
#define NEXPERT 8
#define NFFN 2048
#define EPS_LN 1e-5f
#define EPS_ATTN 1.1920929e-7f

typedef __bf16 bf8v __attribute__((ext_vector_type(8)));
typedef __bf16 bf4v __attribute__((ext_vector_type(4)));
typedef float f4v __attribute__((ext_vector_type(4)));

static __device__ __forceinline__ f4v mfma16(bf8v a, bf8v b, f4v c) {
  return __builtin_amdgcn_mfma_f32_16x16x32_bf16(a, b, c, 0, 0, 0);
}

static __device__ __forceinline__ void gl2lds16(const void* g, void* l) {
  __builtin_amdgcn_global_load_lds(
      (const __attribute__((address_space(1))) unsigned int*)g,
      (__attribute__((address_space(3))) unsigned int*)l, 16, 0, 0);
}

// ---------------- RMSNorm: one row (2048) per 256-thread block ----------------
__global__ __launch_bounds__(256) void rms_kernel(const float* __restrict__ in,
                                                  const float* __restrict__ w,
                                                  __bf16* __restrict__ out_bf,
                                                  const float* __restrict__ gate,
                                                  float* __restrict__ copy_out,
                                                  float* __restrict__ out_f32,
                                                  float eps) {
  const int row = blockIdx.x, tid = threadIdx.x;
  const float* p = in + (size_t)row * NHID;
  float4 v0 = *(const float4*)(p + 4 * tid);
  float4 v1 = *(const float4*)(p + 1024 + 4 * tid);
  float ss = v0.x * v0.x + v0.y * v0.y + v0.z * v0.z + v0.w * v0.w
           + v1.x * v1.x + v1.y * v1.y + v1.z * v1.z + v1.w * v1.w;
  for (int off = 32; off > 0; off >>= 1) ss += __shfl_down(ss, off);
  __shared__ float red[4];
  const int wv = tid >> 6, ln = tid & 63;
  if (ln == 0) red[wv] = ss;
  __syncthreads();
  const float tot = red[0] + red[1] + red[2] + red[3];
  const float rinv = rsqrtf(tot * (1.f / NHID) + eps);
  float4 w0 = *(const float4*)(w + 4 * tid);
  float4 w1 = *(const float4*)(w + 1024 + 4 * tid);
  float4 o0, o1;
  o0.x = v0.x * rinv * w0.x; o0.y = v0.y * rinv * w0.y;
  o0.z = v0.z * rinv * w0.z; o0.w = v0.w * rinv * w0.w;
  o1.x = v1.x * rinv * w1.x; o1.y = v1.y * rinv * w1.y;
  o1.z = v1.z * rinv * w1.z; o1.w = v1.w * rinv * w1.w;
  if (gate) {
    const float* gp = gate + (size_t)row * NHID;
    float4 g0 = *(const float4*)(gp + 4 * tid);
    float4 g1 = *(const float4*)(gp + 1024 + 4 * tid);
    o0.x *= g0.x; o0.y *= g0.y; o0.z *= g0.z; o0.w *= g0.w;
    o1.x *= g1.x; o1.y *= g1.y; o1.z *= g1.z; o1.w *= g1.w;
  }
  bf4v b0, b1;
  b0[0] = (__bf16)o0.x; b0[1] = (__bf16)o0.y; b0[2] = (__bf16)o0.z; b0[3] = (__bf16)o0.w;
  b1[0] = (__bf16)o1.x; b1[1] = (__bf16)o1.y; b1[2] = (__bf16)o1.z; b1[3] = (__bf16)o1.w;
  *(bf4v*)(out_bf + (size_t)row * NHID + 4 * tid) = b0;
  *(bf4v*)(out_bf + (size_t)row * NHID + 1024 + 4 * tid) = b1;
  if (out_f32) {
    *(float4*)(out_f32 + (size_t)row * NHID + 4 * tid) = o0;
    *(float4*)(out_f32 + (size_t)row * NHID + 1024 + 4 * tid) = o1;
  }
  if (copy_out) {
    *(float4*)(copy_out + (size_t)row * NHID + 4 * tid) = v0;
    *(float4*)(copy_out + (size_t)row * NHID + 1024 + 4 * tid) = v1;
  }
}

// ---------------- Generic C = act(A @ B^T) GEMM ----------------
// A: bf16 (producer-converted), staged MRx32x2B via global_load_lds with
//    16B XOR swizzle (chunk ^ (row&3)) -> 1 ds_read_b128/frag, 0 cvt.
// B: fp32 weights, staged 64x32x4B, chunk ^ (row&7) swizzle, cvt at read.
// 3-deep LDS pipeline, counted vmcnt (LW loads/wave/tile), one barrier/step.
// Geometry by MODE: QKV/MOE2 = 128x64; GATE/AOUT = 64x64 (2x blocks -> TLP);
// MOE13 = 128x64 dual-B fused (silu(A@B1^T) * (A@B3^T)).
enum { GM_QKV = 0, GM_GATE = 1, GM_AOUT = 2, GM_MOE13 = 3, GM_MOE2 = 4 };

struct GArgs {
  const __bf16* A; const float* B; const float* B3; void* C;
  const float* res;
  __bf16* q_s; __bf16* k_s; __bf16* v_s;
  const int* perm; const int* segoff; const float* pw;
  float* outp;
  int N, K;
};

template <int MODE>
__global__ __launch_bounds__(256, (MODE == GM_GATE || MODE == GM_AOUT) ? 4
                                  : (MODE == GM_MOE13 ? 2 : 3))
void gemm_bt(GArgs g) {
  constexpr int MR = (MODE == GM_GATE || MODE == GM_AOUT) ? 64 : 128;
  constexpr bool DUAL = (MODE == GM_MOE13);
  constexpr int MI = MR / 32;                       // m-frags per wave
  constexpr int LW = MR / 64 + 2 + (DUAL ? 2 : 0);  // gl2lds per wave per tile

  const int n0 = blockIdx.x * 64;
  const int m0 = blockIdx.y * MR;
  int segbase = 0, cnt = 0x40000000, e = 0;
  if constexpr (MODE >= GM_MOE13) {
    e = blockIdx.z;
    segbase = g.segoff[e];
    cnt = g.segoff[e + 1] - segbase;
    if (m0 >= cnt) return;
  }
  const float* Bp = g.B + (size_t)e * g.N * g.K + (size_t)n0 * g.K;
  const float* Bp3 = nullptr;
  if constexpr (DUAL) Bp3 = g.B3 + (size_t)e * g.N * g.K + (size_t)n0 * g.K;

  __shared__ __bf16 As[3][MR * 32] __attribute__((aligned(16)));
  __shared__ float Bs[3][64 * 32] __attribute__((aligned(16)));
  __shared__ float B3s[DUAL ? 3 : 1][DUAL ? 64 * 32 : 1] __attribute__((aligned(16)));

  const int tid = threadIdx.x;
  const int w = tid >> 6, lane = tid & 63;
  const int wm = (w >> 1) * (MR / 2), wn = (w & 1) * 32;
  const int lm = lane & 15, quad = lane >> 4;
  const int K = g.K;

  // A staging pointers: row r = w*(MR/4) + qi*16 + (lane>>2), chunk (lane&3)^(r&3)
  const __bf16* aptr[MR / 64];
#pragma unroll
  for (int qi = 0; qi < MR / 64; qi++) {
    const int r = w * (MR / 4) + qi * 16 + (lane >> 2);
    const int m = m0 + r;
    long grow;
    if constexpr (MODE == GM_MOE13) {
      int mm = m < cnt ? m : cnt - 1;
      grow = g.perm[segbase + mm];
    } else if constexpr (MODE == GM_MOE2) {
      grow = segbase + (m < cnt ? m : cnt - 1);
    } else {
      grow = m;
    }
    const int gc = (lane & 3) ^ (r & 3);
    aptr[qi] = g.A + (size_t)grow * K + gc * 8;
  }
  // B staging pointers: row (w*2+qi)*8 + (lane>>3), chunk (lane&7)^row
  const float* bptr[2];
  const float* b3ptr[2] = {nullptr, nullptr};
  {
    const int lr = lane >> 3;
    const int coff = ((lane & 7) ^ lr) * 4;
#pragma unroll
    for (int qi = 0; qi < 2; qi++) {
      const int r = (w * 2 + qi) * 8 + lr;
      bptr[qi] = Bp + (size_t)r * K + coff;
      if constexpr (DUAL) b3ptr[qi] = Bp3 + (size_t)r * K + coff;
    }
  }

  const f4v fz = {0.f, 0.f, 0.f, 0.f};
  f4v acc[MI][2];
  f4v acc3[DUAL ? MI : 1][2];
#pragma unroll
  for (int i = 0; i < MI; i++) {
    acc[i][0] = fz; acc[i][1] = fz;
    if constexpr (DUAL) { acc3[i][0] = fz; acc3[i][1] = fz; }
  }

  const int KT = K >> 5;

#define STAGE(tt, bb)                                                     \
  do {                                                                    \
    const int kk_ = (tt) << 5;                                            \
    _Pragma("unroll")                                                     \
    for (int qi = 0; qi < MR / 64; qi++)                                  \
      gl2lds16(aptr[qi] + kk_, &As[bb][(w * (MR / 4) + qi * 16) * 32]);   \
    gl2lds16(bptr[0] + kk_, &Bs[bb][(w * 16) * 32]);                      \
    gl2lds16(bptr[1] + kk_, &Bs[bb][(w * 16 + 8) * 32]);                  \
    if constexpr (DUAL) {                                                 \
      gl2lds16(b3ptr[0] + kk_, &B3s[bb][(w * 16) * 32]);                  \
      gl2lds16(b3ptr[1] + kk_, &B3s[bb][(w * 16 + 8) * 32]);              \
    }                                                                     \
  } while (0)

  // prologue: tiles 0 and 1 in flight
  STAGE(0, 0);
  STAGE(1, 1);

  const int swa = lm & 3;   // A read swizzle (row&3)
  const int swb = lm & 7;   // B read swizzle (row&7)
  for (int t = 0; t < KT; ++t) {
    const int cur = t % 3;
    if (t + 1 < KT) {
      if constexpr (LW == 3)      asm volatile("s_waitcnt vmcnt(3)" ::: "memory");
      else if constexpr (LW == 4) asm volatile("s_waitcnt vmcnt(4)" ::: "memory");
      else                        asm volatile("s_waitcnt vmcnt(6)" ::: "memory");
    } else {
      asm volatile("s_waitcnt vmcnt(0)" ::: "memory");
    }
    __builtin_amdgcn_s_barrier();  // tile t ready; buf (t+2)%3 free
    if (t + 2 < KT) STAGE(t + 2, (t + 2) % 3);
    // ---- compute tile t ----
    bf8v af[MI], bfv[2];
#pragma unroll
    for (int i = 0; i < MI; i++) {
      const int ra = wm + i * 16 + lm;
      af[i] = *(const bf8v*)&As[cur][ra * 32 + ((quad ^ swa) << 3)];
    }
#pragma unroll
    for (int j = 0; j < 2; j++) {
      const int rb = wn + j * 16 + lm;
      const float4 x0 = *(const float4*)&Bs[cur][rb * 32 + (((quad * 2) ^ swb) << 2)];
      const float4 x1 = *(const float4*)&Bs[cur][rb * 32 + (((quad * 2 + 1) ^ swb) << 2)];
      bf8v t8;
      t8[0] = (__bf16)x0.x; t8[1] = (__bf16)x0.y; t8[2] = (__bf16)x0.z; t8[3] = (__bf16)x0.w;
      t8[4] = (__bf16)x1.x; t8[5] = (__bf16)x1.y; t8[6] = (__bf16)x1.z; t8[7] = (__bf16)x1.w;
      bfv[j] = t8;
    }
#pragma unroll
    for (int i = 0; i < MI; i++)
#pragma unroll
      for (int j = 0; j < 2; j++) acc[i][j] = mfma16(af[i], bfv[j], acc[i][j]);
    if constexpr (DUAL) {
      bf8v b3v[2];
#pragma unroll
      for (int j = 0; j < 2; j++) {
        const int rb = wn + j * 16 + lm;
        const float4 x0 = *(const float4*)&B3s[cur][rb * 32 + (((quad * 2) ^ swb) << 2)];
        const float4 x1 = *(const float4*)&B3s[cur][rb * 32 + (((quad * 2 + 1) ^ swb) << 2)];
        bf8v t8;
        t8[0] = (__bf16)x0.x; t8[1] = (__bf16)x0.y; t8[2] = (__bf16)x0.z; t8[3] = (__bf16)x0.w;
        t8[4] = (__bf16)x1.x; t8[5] = (__bf16)x1.y; t8[6] = (__bf16)x1.z; t8[7] = (__bf16)x1.w;
        b3v[j] = t8;
      }
#pragma unroll
      for (int i = 0; i < MI; i++)
#pragma unroll
        for (int j = 0; j < 2; j++) acc3[i][j] = mfma16(af[i], b3v[j], acc3[i][j]);
    }
  }
#undef STAGE

#pragma unroll
  for (int i = 0; i < MI; i++) {
#pragma unroll
    for (int r = 0; r < 4; r++) {
      const int m = m0 + wm + i * 16 + quad * 4 + r;
      int tok = 0;
      float wgt = 0.f;
      if constexpr (MODE == GM_MOE2) {
        if (m < cnt) { tok = g.perm[segbase + m]; wgt = g.pw[segbase + m]; }
      }
#pragma unroll
      for (int j = 0; j < 2; j++) {
        const int col = n0 + wn + j * 16 + lm;
        float v = acc[i][j][r];
        if constexpr (MODE == GM_QKV) {
          v = v / (1.f + expf(-v));
          int head = col / 384;
          int rem = col - head * 384;
          int which = rem >> 7;
          int d = rem & 127;
          __bf16* dst = which == 0 ? g.q_s : (which == 1 ? g.k_s : g.v_s);
          dst[((size_t)head * NTOK + m) * DHEAD + d] = (__bf16)v;
        } else if constexpr (MODE == GM_GATE) {
          ((float*)g.C)[(size_t)m * g.N + col] = 1.f / (1.f + expf(-v));
        } else if constexpr (MODE == GM_AOUT) {
          ((float*)g.C)[(size_t)m * g.N + col] = v + g.res[(size_t)m * g.N + col];
        } else if constexpr (MODE == GM_MOE13) {
          if (m < cnt) {
            float s1 = v / (1.f + expf(-v));
            ((__bf16*)g.C)[(size_t)(segbase + m) * g.N + col] = (__bf16)(s1 * acc3[i][j][r]);
          }
        } else if constexpr (MODE == GM_MOE2) {
          if (m < cnt) atomicAdd(&g.outp[(size_t)tok * NHID + col], wgt * v);
        }
      }
    }
  }
}

// ---------------- Lightning attention pass 1: S(h,b) = (k*kdecay)^T @ v ----------------
__global__ __launch_bounds__(512) void attn_pass1(const __bf16* __restrict__ k_s,
                                                  const __bf16* __restrict__ v_s,
                                                  const float* __restrict__ slope,
                                                  float* __restrict__ S) {
  const int h = blockIdx.x >> 2, b = blockIdx.x & 3;
  const float s = slope[h];
  __shared__ __bf16 kT[128][40] __attribute__((aligned(16)));
  __shared__ __bf16 vT[128][40] __attribute__((aligned(16)));
  const int tid = threadIdx.x, wave = tid >> 6, lane = tid & 63;
  const int lm = lane & 15, quad = lane >> 4;
  const __bf16* kb = k_s + ((size_t)h * NTOK + b * ABLK) * DHEAD;
  const __bf16* vb = v_s + ((size_t)h * NTOK + b * ABLK) * DHEAD;
  const int sd = tid & 127, sg = (tid >> 7) * 8;
  const f4v fz = {0.f, 0.f, 0.f, 0.f};
  f4v acc[8];
#pragma unroll
  for (int j = 0; j < 8; j++) acc[j] = fz;
  for (int ic = 0; ic < 8; ic++) {
    __syncthreads();
    bf8v kq, vq;
#pragma unroll
    for (int ii = 0; ii < 8; ii++) {
      int ig = ic * 32 + sg + ii;
      float kd = expf(-s * (float)(ABLK - 1 - ig));
      kq[ii] = (__bf16)((float)kb[(size_t)ig * DHEAD + sd] * kd);
      vq[ii] = vb[(size_t)ig * DHEAD + sd];
    }
    *(bf8v*)&kT[sd][sg] = kq;
    *(bf8v*)&vT[sd][sg] = vq;
    __syncthreads();
    bf8v a = *(const bf8v*)&kT[wave * 16 + lm][quad * 8];
#pragma unroll
    for (int j = 0; j < 8; j++) {
      bf8v bb = *(const bf8v*)&vT[j * 16 + lm][quad * 8];
      acc[j] = mfma16(a, bb, acc[j]);
    }
  }
  float* Sp = S + (size_t)(h * 4 + b) * (128 * 128);
#pragma unroll
  for (int j = 0; j < 8; j++)
#pragma unroll
    for (int r = 0; r < 4; r++)
      Sp[(size_t)(wave * 16 + quad * 4 + r) * 128 + j * 16 + lm] = acc[j][r];
}

// ---------------- Lightning attention pass 2: o = qdecay*(q@kv_in) + (qk*diag)@v ----------------
__global__ __launch_bounds__(512) void attn_pass2(const __bf16* __restrict__ q_s,
                                                  const __bf16* __restrict__ k_s,
                                                  const __bf16* __restrict__ v_s,
                                                  const float* __restrict__ slope,
                                                  const float* __restrict__ S,
                                                  float* __restrict__ attn_raw) {
  const int h = blockIdx.x >> 2, b = blockIdx.x & 3;
  const float s = slope[h];
  __shared__ __bf16 kvb[128][136] __attribute__((aligned(16)));  // [e][d]
  __shared__ __bf16 vT[128][40] __attribute__((aligned(16)));    // [e][i-chunk]
  __shared__ __bf16 ki[32][136] __attribute__((aligned(16)));    // [i][d]
  __shared__ __bf16 qkb[256][40] __attribute__((aligned(16)));   // [m][i-chunk]
  const int tid = threadIdx.x, w = tid >> 6, lane = tid & 63;
  const int lm = lane & 15, quad = lane >> 4;
  // ---- build decayed KV prefix state in B-layout ----
  {
    const int sd = tid >> 2;
    const int e0 = (tid & 3) * 32;
    float vals[32];
#pragma unroll
    for (int u = 0; u < 32; u++) vals[u] = 0.f;
    for (int j = 0; j < b; j++) {
      float c = expf(-s * 256.f * (float)(b - 1 - j));
      const float* Sp = S + (size_t)(h * 4 + j) * (128 * 128) + (size_t)sd * 128 + e0;
#pragma unroll
      for (int u4 = 0; u4 < 8; u4++) {
        float4 sv = *(const float4*)(Sp + u4 * 4);
        vals[u4 * 4 + 0] += c * sv.x; vals[u4 * 4 + 1] += c * sv.y;
        vals[u4 * 4 + 2] += c * sv.z; vals[u4 * 4 + 3] += c * sv.w;
      }
    }
#pragma unroll
    for (int u = 0; u < 32; u++) kvb[e0 + u][sd] = (__bf16)vals[u];
  }
  __syncthreads();
  const __bf16* qb = q_s + ((size_t)h * NTOK + b * ABLK) * DHEAD;
  const __bf16* kb = k_s + ((size_t)h * NTOK + b * ABLK) * DHEAD;
  const __bf16* vb = v_s + ((size_t)h * NTOK + b * ABLK) * DHEAD;
  // ---- q fragments (raw, no decay) ----
  bf8v aq[2][4];
#pragma unroll
  for (int mf = 0; mf < 2; mf++) {
    const int m = w * 32 + mf * 16 + lm;
#pragma unroll
    for (int kc = 0; kc < 4; kc++)
      aq[mf][kc] = *(const bf8v*)(qb + (size_t)m * DHEAD + kc * 32 + quad * 8);
  }
  const f4v fz = {0.f, 0.f, 0.f, 0.f};
  f4v accO[2][8];
#pragma unroll
  for (int mf = 0; mf < 2; mf++)
#pragma unroll
    for (int nf = 0; nf < 8; nf++) accO[mf][nf] = fz;
  // ---- o_nd = q @ kv_in ----
#pragma unroll
  for (int kc = 0; kc < 4; kc++) {
#pragma unroll
    for (int nf = 0; nf < 8; nf++) {
      bf8v bb = *(const bf8v*)&kvb[nf * 16 + lm][kc * 32 + quad * 8];
      accO[0][nf] = mfma16(aq[0][kc], bb, accO[0][nf]);
      accO[1][nf] = mfma16(aq[1][kc], bb, accO[1][nf]);
    }
  }
  // scale rows by q_decay
#pragma unroll
  for (int mf = 0; mf < 2; mf++) {
#pragma unroll
    for (int r = 0; r < 4; r++) {
      const int m = w * 32 + mf * 16 + quad * 4 + r;
      const float qd = expf(-s * (float)(m + 1));
#pragma unroll
      for (int nf = 0; nf < 8; nf++) accO[mf][nf][r] *= qd;
    }
  }
  // ---- intra-block: chunks of 32 keys ----
  for (int ic = 0; ic < 8; ic++) {
    __syncthreads();
    {
      const int si = tid >> 4, dc = (tid & 15) * 8;
      *(bf8v*)&ki[si][dc] = *(const bf8v*)(kb + (size_t)(ic * 32 + si) * DHEAD + dc);
    }
    {
      const int se = tid & 127, sg = (tid >> 7) * 8;
      bf8v t;
#pragma unroll
      for (int ii = 0; ii < 8; ii++)
        t[ii] = vb[(size_t)(ic * 32 + sg + ii) * DHEAD + se];
      *(bf8v*)&vT[se][sg] = t;
    }
    __syncthreads();
    f4v acc2[2][2];
    acc2[0][0] = fz; acc2[0][1] = fz; acc2[1][0] = fz; acc2[1][1] = fz;
#pragma unroll
    for (int kc = 0; kc < 4; kc++) {
#pragma unroll
      for (int f = 0; f < 2; f++) {
        bf8v bk = *(const bf8v*)&ki[f * 16 + lm][kc * 32 + quad * 8];
        acc2[0][f] = mfma16(aq[0][kc], bk, acc2[0][f]);
        acc2[1][f] = mfma16(aq[1][kc], bk, acc2[1][f]);
      }
    }
#pragma unroll
    for (int mf = 0; mf < 2; mf++) {
#pragma unroll
      for (int f = 0; f < 2; f++) {
#pragma unroll
        for (int r = 0; r < 4; r++) {
          const int m = w * 32 + mf * 16 + quad * 4 + r;
          const int i = ic * 32 + f * 16 + lm;
          float v = acc2[mf][f][r];
          v = (m >= i) ? v * expf(-s * (float)(m - i)) : 0.f;
          qkb[m][f * 16 + lm] = (__bf16)v;
        }
      }
    }
    __syncthreads();
#pragma unroll
    for (int mf = 0; mf < 2; mf++) {
      bf8v aqk = *(const bf8v*)&qkb[w * 32 + mf * 16 + lm][quad * 8];
#pragma unroll
      for (int nf = 0; nf < 8; nf++) {
        bf8v bv = *(const bf8v*)&vT[nf * 16 + lm][quad * 8];
        accO[mf][nf] = mfma16(aqk, bv, accO[mf][nf]);
      }
    }
  }
  float* op = attn_raw + (size_t)(b * ABLK) * NHID + h * DHEAD;
#pragma unroll
  for (int mf = 0; mf < 2; mf++)
#pragma unroll
    for (int r = 0; r < 4; r++) {
      const int m = w * 32 + mf * 16 + quad * 4 + r;
#pragma unroll
      for (int nf = 0; nf < 8; nf++)
        op[(size_t)m * NHID + nf * 16 + lm] = accO[mf][nf][r];
    }
}

// ---------------- Router: fp32 logits, top-2 ----------------
__global__ __launch_bounds__(256) void router_kernel(const float* __restrict__ h2,
                                                     const float* __restrict__ rw,
                                                     int* __restrict__ eidx,
                                                     float* __restrict__ ew) {
  const int wave = threadIdx.x >> 6, lane = threadIdx.x & 63;
  const int t = blockIdx.x * 4 + wave;
  float a[8];
#pragma unroll
  for (int e = 0; e < 8; e++) a[e] = 0.f;
  for (int d = lane; d < NHID; d += 64) {
    float xv = h2[(size_t)t * NHID + d];
#pragma unroll
    for (int e = 0; e < 8; e++) a[e] += xv * rw[(size_t)e * NHID + d];
  }
#pragma unroll
  for (int e = 0; e < 8; e++)
    for (int off = 32; off > 0; off >>= 1) a[e] += __shfl_down(a[e], off);
  if (lane == 0) {
    int i1 = 0;
#pragma unroll
    for (int e = 1; e < 8; e++)
      if (a[e] > a[i1]) i1 = e;
    int i2 = i1 == 0 ? 1 : 0;
#pragma unroll
    for (int e = 0; e < 8; e++) {
      if (e == i1 || e == i2) continue;
      if (a[e] > a[i2]) i2 = e;
    }
    float be = expf(a[i2] - a[i1]);
    float w1 = 1.f / (1.f + be), w2 = be / (1.f + be);
    eidx[2 * t] = i1; eidx[2 * t + 1] = i2;
    ew[2 * t] = w1; ew[2 * t + 1] = w2;
  }
}

__global__ __launch_bounds__(256) void build_lists(const int* __restrict__ eidx,
                                                   const float* __restrict__ ew,
                                                   int* __restrict__ segoff,
                                                   int* __restrict__ perm,
                                                   float* __restrict__ pw) {
  __shared__ int cnt[8], cur[8], offs[9];
  const int tid = threadIdx.x;
  if (tid < 8) cnt[tid] = 0;
  __syncthreads();
  for (int t = tid; t < NTOK; t += 256) {
    atomicAdd(&cnt[eidx[2 * t]], 1);
    atomicAdd(&cnt[eidx[2 * t + 1]], 1);
  }
  __syncthreads();
  if (tid == 0) {
    int o = 0;
    for (int e = 0; e < 8; e++) { offs[e] = o; o += cnt[e]; }
    offs[8] = o;
    for (int e = 0; e < 9; e++) segoff[e] = offs[e];
  }
  __syncthreads();
  if (tid < 8) cur[tid] = offs[tid];
  __syncthreads();
  for (int t = tid; t < NTOK; t += 256) {
    for (int k = 0; k < 2; k++) {
      int e = eidx[2 * t + k];
      int pos = atomicAdd(&cur[e], 1);
      perm[pos] = t;
      pw[pos] = ew[2 * t + k];
    }
  }
}

// ---------------- launch ----------------
extern "C" void kernel_launch(void* const* d_in, const int* in_sizes, int n_in,
                              void* d_out, int out_size, void* d_ws, size_t ws_size,
                              hipStream_t stream) {
  (void)in_sizes; (void)n_in; (void)out_size; (void)ws_size;
  const float* x        = (const float*)d_in[0];
  const float* slope    = (const float*)d_in[1];
  const float* ln1_w    = (const float*)d_in[2];
  const float* ln2_w    = (const float*)d_in[3];
  const float* qkv_w    = (const float*)d_in[4];
  const float* ogate_w  = (const float*)d_in[5];
  const float* anorm_w  = (const float*)d_in[6];
  const float* aout_w   = (const float*)d_in[7];
  const float* router_w = (const float*)d_in[8];
  const float* w1       = (const float*)d_in[9];
  const float* w2       = (const float*)d_in[10];
  const float* w3       = (const float*)d_in[11];
  float* out = (float*)d_out;
  float* ws  = (float*)d_ws;

  const size_t MW = (size_t)NTOK * NHID;  // 2M floats
  __bf16* a_ln   = (__bf16*)ws;
  __bf16* q_s    = (__bf16*)(ws + MW);
  __bf16* k_s    = (__bf16*)(ws + 2 * MW);
  __bf16* v_s    = (__bf16*)(ws + 3 * MW);
  float* Sbuf    = ws + 4 * MW;
  float* attn_raw = ws + 4 * MW + MW / 2;
  float* gatebuf  = ws + 5 * MW + MW / 2;
  __bf16* t1     = (__bf16*)attn_raw;
  float* h2f     = gatebuf;
  float* rbase   = ws + 6 * MW + MW / 2;
  int*   eidx   = (int*)rbase;
  float* ew     = rbase + 2048;
  int*   segoff = (int*)(rbase + 4096);
  int*   perm   = (int*)(rbase + 4112);
  float* pw     = rbase + 6160;
  float* h_res  = ws + 2 * MW;
  __bf16* h2    = v_s;
  __bf16* ag    = a_ln;

  // 1. ln1 -> bf16
  rms_kernel<<<dim3(NTOK), dim3(256), 0, stream>>>(x, ln1_w, a_ln, nullptr, nullptr, nullptr, EPS_LN);
  // 2. qkv = silu(a_ln @ qkv_w^T), split to bf16 q/k/v [h][t][d]
  {
    GArgs g{}; g.A = a_ln; g.B = qkv_w; g.q_s = q_s; g.k_s = k_s; g.v_s = v_s;
    g.N = NQKV; g.K = NHID;
    gemm_bt<GM_QKV><<<dim3(NQKV / 64, NTOK / 128), dim3(256), 0, stream>>>(g);
  }
  // 3/4. attention (bf16 q/k/v)
  attn_pass1<<<dim3(64), dim3(512), 0, stream>>>(k_s, v_s, slope, Sbuf);
  attn_pass2<<<dim3(64), dim3(512), 0, stream>>>(q_s, k_s, v_s, slope, Sbuf, attn_raw);
  // 5. gate = sigmoid(a_ln @ ogate_w^T)  (fp32 out, 64-row tile for TLP)
  {
    GArgs g{}; g.A = a_ln; g.B = ogate_w; g.C = gatebuf; g.N = NHID; g.K = NHID;
    gemm_bt<GM_GATE><<<dim3(32, 16), dim3(256), 0, stream>>>(g);
  }
  // 6. ag = rmsnorm(attn_raw)*anorm_w*gate -> bf16 (overwrites a_ln)
  rms_kernel<<<dim3(NTOK), dim3(256), 0, stream>>>(attn_raw, anorm_w, ag, gatebuf, nullptr, nullptr, EPS_ATTN);
  // 7. h_res = ag @ aout_w^T + x  (fp32, 64-row tile)
  {
    GArgs g{}; g.A = ag; g.B = aout_w; g.C = h_res; g.res = x; g.N = NHID; g.K = NHID;
    gemm_bt<GM_AOUT><<<dim3(32, 16), dim3(256), 0, stream>>>(g);
  }
  // 8. h2 = rmsnorm(h_res, ln2) -> bf16 + fp32 (router); out = h_res copy
  rms_kernel<<<dim3(NTOK), dim3(256), 0, stream>>>(h_res, ln2_w, h2, nullptr, out, h2f, EPS_LN);
  // 9. router (fp32 h2)
  router_kernel<<<dim3(NTOK / 4), dim3(256), 0, stream>>>(h2f, router_w, eidx, ew);
  // 10. bucket tokens by expert
  build_lists<<<dim3(1), dim3(256), 0, stream>>>(eidx, ew, segoff, perm, pw);
  // 11+12 fused. t1 = silu(h2[gather] @ w1^T) * (h2[gather] @ w3^T) -> bf16
  {
    GArgs g{}; g.A = h2; g.B = w1; g.B3 = w3; g.C = t1; g.perm = perm; g.segoff = segoff;
    g.N = NFFN; g.K = NHID;
    gemm_bt<GM_MOE13><<<dim3(32, 16, 8), dim3(256), 0, stream>>>(g);
  }
  // 13. out[token] += weight * (t1 @ w2^T)
  {
    GArgs g{}; g.A = t1; g.B = w2; g.outp = out; g.perm = perm; g.segoff = segoff; g.pw = pw;
    g.N = NHID; g.K = NFFN;
    gemm_bt<GM_MOE2><<<dim3(32, 16, 8), dim3(256), 0, stream>>>(g);
  }
}